// Round 2
// baseline (283.250 us; speedup 1.0000x reference)
//
#include <hip/hip_runtime.h>

#define SEQ 4096
#define DM  1024
#define DH  64
#define NB  4
#define SLOTS_PER_B 288   // sum_{qt=0}^{63} ceil((qt+1)/8)

typedef __attribute__((ext_vector_type(4))) float  f32x4;
typedef __attribute__((ext_vector_type(8))) __bf16 bf16x8;

__device__ __forceinline__ unsigned short f2bf(float f) {
    unsigned int u = __float_as_uint(f);
    u += 0x7FFFu + ((u >> 16) & 1u);          // RNE
    return (unsigned short)(u >> 16);
}

// native fptrunc -> lets the compiler emit v_cvt_pk_bf16_f32 for pairs (RNE)
__device__ __forceinline__ unsigned short bfc(float f) {
    __bf16 h = (__bf16)f;
    return __builtin_bit_cast(unsigned short, h);
}

__device__ __forceinline__ f32x4 mfma_bf16(bf16x8 a, bf16x8 b, f32x4 c) {
    return __builtin_amdgcn_mfma_f32_16x16x32_bf16(a, b, c, 0, 0, 0);
}

__device__ __forceinline__ void gload_lds16(const void* g, void* l) {
    __builtin_amdgcn_global_load_lds(
        (const __attribute__((address_space(1))) void*)g,
        (__attribute__((address_space(3))) void*)l, 16, 0, 0);
}

// ---------------------------------------------------------------------------
// W pre-convert: W[64][1024] fp32 -> bf16 in MFMA B-fragment order.
// Wf[which][kc(16)][ks(2)][nt(4)][lane(64)][8], elem = W[nt*16+l16][kc*64+ks*32+quad*8+j]
// ---------------------------------------------------------------------------
__global__ __launch_bounds__(256) void wprep_kernel(
    const float* __restrict__ Wq, const float* __restrict__ Wk, const float* __restrict__ Wv,
    unsigned short* __restrict__ Wf)
{
    const int which = blockIdx.y;
    const int kc    = blockIdx.x;                 // 0..15
    const float* W  = (which == 0) ? Wq : (which == 1) ? Wk : Wv;
    unsigned short* out = Wf + (size_t)which * 65536 + (size_t)kc * 4096;
    const int t = threadIdx.x;
#pragma unroll
    for (int s = t; s < 512; s += 256) {
        const int ks = s >> 8, nt = (s >> 6) & 3, ln = s & 63;
        const int qd = ln >> 4, l = ln & 15;
        const float* src = W + (size_t)(nt * 16 + l) * DM + kc * 64 + ks * 32 + qd * 8;
        f32x4 v0 = *(const f32x4*)src;
        f32x4 v1 = *(const f32x4*)(src + 4);
        *(ushort4*)(out + (size_t)s * 8)     = make_ushort4(bfc(v0[0]), bfc(v0[1]), bfc(v0[2]), bfc(v0[3]));
        *(ushort4*)(out + (size_t)s * 8 + 4) = make_ushort4(bfc(v1[0]), bfc(v1[1]), bfc(v1[2]), bfc(v1[3]));
    }
}

// ---------------------------------------------------------------------------
// Projection: Y = X[16384,1024] @ W[64,1024]^T + b  -> bf16
//   which=0: qh [B*S][64]; which=1: kh [B*S][64]; which=2: vhT [B][64][S]
// Counted-vmcnt pipeline: dbuf LDS, ONE raw s_barrier per K-chunk, X register
// prefetch 2 chunks deep (stays in flight across barriers), W staged with
// global_load_lds from the pre-converted fragment-layout buffer.
// sched_barrier(0) pins the glds-before-X-prefetch issue order so the
// counted vmcnt(4) FIFO arithmetic is deterministic.
// ---------------------------------------------------------------------------
__global__ __launch_bounds__(256) void proj_kernel(
    const float* __restrict__ xq, const float* __restrict__ xk, const float* __restrict__ xv,
    const unsigned short* __restrict__ Wf,
    const float* __restrict__ bq, const float* __restrict__ bk, const float* __restrict__ bv,
    unsigned short* __restrict__ qh, unsigned short* __restrict__ kh,
    unsigned short* __restrict__ vhT)
{
    __shared__ unsigned short x_t[2][64][72];   // pad 72: 16B-aligned rows
    __shared__ unsigned short wfb[2][4096];     // bf16 B-fragments, linear

    const int which = blockIdx.y;
    const float* X  = (which == 0) ? xq : (which == 1) ? xk : xv;
    const float* Bb = (which == 0) ? bq : (which == 1) ? bk : bv;
    const unsigned short* Wg = Wf + (size_t)which * 65536;

    const int m0   = blockIdx.x * 64;
    const int t    = threadIdx.x;
    const int wv   = t >> 6;
    const int lane = t & 63;
    const int quad = lane >> 4;
    const int l16  = lane & 15;
    const int sr   = t >> 2;           // staging row 0..63
    const int sc   = (t & 3) << 4;     // staging col chunk {0,16,32,48}

    f32x4 acc[4];
#pragma unroll
    for (int i = 0; i < 4; ++i) acc[i] = f32x4{0.f, 0.f, 0.f, 0.f};

    const float* xg = X + (size_t)(m0 + sr) * DM + sc;

    f32x4 xr[2][4];
    // ---- prologue: X chunks 0,1 in regs; W chunk 0 via glds; stage chunk 0 ----
#pragma unroll
    for (int i = 0; i < 4; ++i) xr[0][i] = *(const f32x4*)(xg + i * 4);
#pragma unroll
    for (int i = 0; i < 4; ++i) xr[1][i] = *(const f32x4*)(xg + 64 + i * 4);
    {
        const unsigned short* gs = Wg + (wv * 2) * 512 + lane * 8;
        gload_lds16(gs,       &wfb[0][(wv * 2) * 512]);
        gload_lds16(gs + 512, &wfb[0][(wv * 2) * 512 + 512]);
    }
    __builtin_amdgcn_sched_barrier(0);   // pin: glds issued before anything below
#pragma unroll
    for (int i = 0; i < 4; ++i) {
        f32x4 v = xr[0][i];
        *(ushort4*)&x_t[0][sr][sc + i * 4] =
            make_ushort4(bfc(v[0]), bfc(v[1]), bfc(v[2]), bfc(v[3]));
    }
#pragma unroll
    for (int i = 0; i < 4; ++i) xr[0][i] = *(const f32x4*)(xg + 128 + i * 4);  // chunk 2
    asm volatile("s_waitcnt vmcnt(4)" ::: "memory");   // drain X1 + W0, keep X2
    asm volatile("s_waitcnt lgkmcnt(0)" ::: "memory");
    __builtin_amdgcn_s_barrier();

    // ---- main loop: iter j computes chunk j from bufs [j&1] ----
#pragma unroll
    for (int j = 0; j < 16; ++j) {
        const int cur = j & 1, nxt = cur ^ 1;
        if (j + 1 < 16) {
            // stage chunk j+1 (regs already completed by last iter's vmcnt)
#pragma unroll
            for (int i = 0; i < 4; ++i) {
                f32x4 v = xr[nxt][i];
                *(ushort4*)&x_t[nxt][sr][sc + i * 4] =
                    make_ushort4(bfc(v[0]), bfc(v[1]), bfc(v[2]), bfc(v[3]));
            }
            const unsigned short* gs = Wg + (size_t)(j + 1) * 4096 + (wv * 2) * 512 + lane * 8;
            gload_lds16(gs,       &wfb[nxt][(wv * 2) * 512]);
            gload_lds16(gs + 512, &wfb[nxt][(wv * 2) * 512 + 512]);
        }
        __builtin_amdgcn_sched_barrier(0);   // glds before X prefetch: FIFO order
        if (j + 3 < 16) {   // X prefetch, 2 chunks deep
            const float* xn = xg + (j + 3) * 64;
#pragma unroll
            for (int i = 0; i < 4; ++i) xr[nxt][i] = *(const f32x4*)(xn + i * 4);
        }
        // compute chunk j (both bufs guaranteed by previous vmcnt+barrier)
        bf16x8 a0 = *(const bf16x8*)&x_t[cur][wv * 16 + l16][quad * 8];
        bf16x8 a1 = *(const bf16x8*)&x_t[cur][wv * 16 + l16][32 + quad * 8];
#pragma unroll
        for (int nt = 0; nt < 4; ++nt) {
            bf16x8 b0 = *(const bf16x8*)&wfb[cur][(nt * 64 + lane) * 8];
            acc[nt] = mfma_bf16(a0, b0, acc[nt]);
        }
#pragma unroll
        for (int nt = 0; nt < 4; ++nt) {
            bf16x8 b1 = *(const bf16x8*)&wfb[cur][((4 + nt) * 64 + lane) * 8];
            acc[nt] = mfma_bf16(a1, b1, acc[nt]);
        }
        // steady state FIFO: [X(j+2) 4][W(j+1) 2][X(j+3) 4] -> vmcnt(4) drains
        // X(j+2)+W(j+1) (needed at next iter), keeps X(j+3) in flight.
        if (j < 13) asm volatile("s_waitcnt vmcnt(4)" ::: "memory");
        else        asm volatile("s_waitcnt vmcnt(0)" ::: "memory");
        asm volatile("s_waitcnt lgkmcnt(0)" ::: "memory");
        __builtin_amdgcn_s_barrier();
    }

    // ---- epilogue (unchanged logic; x_t[0] as staging) ----
#pragma unroll
    for (int nt = 0; nt < 4; ++nt) {
        float bias = Bb[nt * 16 + l16];
#pragma unroll
        for (int r = 0; r < 4; ++r)
            x_t[0][wv * 16 + quad * 4 + r][nt * 16 + l16] = f2bf(acc[nt][r] + bias);
    }
    __syncthreads();

    if (which < 2) {
        unsigned short* out = (which == 0) ? qh : kh;
        unsigned short* og  = out + (size_t)(m0 + sr) * DH + sc;
        *(int4*)og       = *(const int4*)&x_t[0][sr][sc];
        *(int4*)(og + 8) = *(const int4*)&x_t[0][sr][sc + 8];
    } else {
        const int bb = m0 >> 12;
        const int s0 = m0 & 4095;
        const int h  = sr;
        const int r0 = sc;
        __align__(16) unsigned short tmp[16];
#pragma unroll
        for (int i = 0; i < 16; ++i) tmp[i] = x_t[0][r0 + i][h];
        unsigned short* og = vhT + (size_t)bb * DH * SEQ + (size_t)h * SEQ + (s0 + r0);
        *(int4*)og       = *(const int4*)&tmp[0];
        *(int4*)(og + 8) = *(const int4*)&tmp[8];
    }
}

// ---------------------------------------------------------------------------
// Flash attention, causal, SPLIT-K over key chunks of 8 tiles (512 keys).
// (unchanged this round)
// ---------------------------------------------------------------------------
__global__ __launch_bounds__(256) void attn_split_kernel(
    const unsigned short* __restrict__ qh, const unsigned short* __restrict__ kh,
    const unsigned short* __restrict__ vhT,
    float* __restrict__ pO, float* __restrict__ pm, float* __restrict__ pl)
{
    const int chunk = blockIdx.x;
    const int qt    = blockIdx.y;
    const int b     = blockIdx.z;
    const int nc    = (qt + 8) >> 3;
    if (chunk >= nc) return;

    const int g = qt >> 3, rr = qt & 7;
    const int slot = b * SLOTS_PER_B + 4 * g * (g + 1) + rr * (g + 1) + chunk;
    const int c0 = chunk * 8;
    const int c1 = min(c0 + 8, qt + 1);

    __shared__ unsigned short k_t[64][72];
    __shared__ unsigned short v_t[64][72];
    __shared__ unsigned short qp[64][72];

    const int t    = threadIdx.x;
    const int wv   = t >> 6;
    const int lane = t & 63;
    const int quad = lane >> 4;
    const int l16  = lane & 15;
    const int sr   = t >> 2;
    const int sc   = (t & 3) << 4;

    const size_t base = (size_t)b * SEQ * DH;

    {   // stage Q tile
        const unsigned short* gq = qh + base + (size_t)(qt * 64 + sr) * DH + sc;
        *(int4*)&qp[sr][sc]     = *(const int4*)gq;
        *(int4*)&qp[sr][sc + 8] = *(const int4*)(gq + 8);
    }
    __syncthreads();
    bf16x8 qfrag[2];
    qfrag[0] = *(const bf16x8*)&qp[wv * 16 + l16][quad * 8];
    qfrag[1] = *(const bf16x8*)&qp[wv * 16 + l16][32 + quad * 8];

    f32x4 o_acc[4];
#pragma unroll
    for (int i = 0; i < 4; ++i) o_acc[i] = f32x4{0.f, 0.f, 0.f, 0.f};
    float m_i[4], l_i[4];
#pragma unroll
    for (int r = 0; r < 4; ++r) { m_i[r] = -1e30f; l_i[r] = 0.f; }

    const int rowb = wv * 16 + quad * 4;

    for (int jt = c0; jt < c1; ++jt) {
        __syncthreads();
        {
            const unsigned short* kg = kh + base + (size_t)(jt * 64 + sr) * DH + sc;
            *(int4*)&k_t[sr][sc]     = *(const int4*)kg;
            *(int4*)&k_t[sr][sc + 8] = *(const int4*)(kg + 8);
            const unsigned short* vg = vhT + (size_t)b * DH * SEQ + (size_t)sr * SEQ + (jt * 64 + sc);
            *(int4*)&v_t[sr][sc]     = *(const int4*)vg;
            *(int4*)&v_t[sr][sc + 8] = *(const int4*)(vg + 8);
        }
        __syncthreads();

        f32x4 s_acc[4];
#pragma unroll
        for (int i = 0; i < 4; ++i) s_acc[i] = f32x4{0.f, 0.f, 0.f, 0.f};
#pragma unroll
        for (int ks = 0; ks < 2; ++ks) {
#pragma unroll
            for (int nt = 0; nt < 4; ++nt) {
                bf16x8 bfr = *(const bf16x8*)&k_t[nt * 16 + l16][ks * 32 + quad * 8];
                s_acc[nt] = mfma_bf16(qfrag[ks], bfr, s_acc[nt]);
            }
        }

        const bool diag = (jt == qt);
#pragma unroll
        for (int nt = 0; nt < 4; ++nt) {
            const int col = nt * 16 + l16;
#pragma unroll
            for (int r = 0; r < 4; ++r) {
                float sv = s_acc[nt][r] * 0.125f;
                if (diag && (col > rowb + r)) sv = -1e30f;
                s_acc[nt][r] = sv;
            }
        }

        float mx[4];
#pragma unroll
        for (int r = 0; r < 4; ++r)
            mx[r] = fmaxf(fmaxf(s_acc[0][r], s_acc[1][r]), fmaxf(s_acc[2][r], s_acc[3][r]));
#pragma unroll
        for (int off = 1; off < 16; off <<= 1)
#pragma unroll
            for (int r = 0; r < 4; ++r)
                mx[r] = fmaxf(mx[r], __shfl_xor(mx[r], off, 64));

        float alpha[4];
#pragma unroll
        for (int r = 0; r < 4; ++r) {
            float mn = fmaxf(m_i[r], mx[r]);
            alpha[r] = __expf(m_i[r] - mn);
            m_i[r]   = mn;
        }

        float rs[4] = {0.f, 0.f, 0.f, 0.f};
#pragma unroll
        for (int nt = 0; nt < 4; ++nt)
#pragma unroll
            for (int r = 0; r < 4; ++r) {
                float p = __expf(s_acc[nt][r] - m_i[r]);
                s_acc[nt][r] = p;
                rs[r] += p;
            }
#pragma unroll
        for (int off = 1; off < 16; off <<= 1)
#pragma unroll
            for (int r = 0; r < 4; ++r)
                rs[r] += __shfl_xor(rs[r], off, 64);
#pragma unroll
        for (int r = 0; r < 4; ++r) l_i[r] = l_i[r] * alpha[r] + rs[r];

#pragma unroll
        for (int nt = 0; nt < 4; ++nt)
#pragma unroll
            for (int r = 0; r < 4; ++r)
                qp[rowb + r][nt * 16 + l16] = f2bf(s_acc[nt][r]);

#pragma unroll
        for (int nt = 0; nt < 4; ++nt)
#pragma unroll
            for (int r = 0; r < 4; ++r)
                o_acc[nt][r] *= alpha[r];

#pragma unroll
        for (int ks = 0; ks < 2; ++ks) {
            bf16x8 pa = *(const bf16x8*)&qp[wv * 16 + l16][ks * 32 + quad * 8];
#pragma unroll
            for (int nt = 0; nt < 4; ++nt) {
                bf16x8 vb = *(const bf16x8*)&v_t[nt * 16 + l16][ks * 32 + quad * 8];
                o_acc[nt] = mfma_bf16(pa, vb, o_acc[nt]);
            }
        }
    }

    // write unnormalized partials
    float* po = pO + (size_t)slot * 4096;
#pragma unroll
    for (int nt = 0; nt < 4; ++nt)
#pragma unroll
        for (int r = 0; r < 4; ++r)
            po[(rowb + r) * 64 + nt * 16 + l16] = o_acc[nt][r];
    if (l16 == 0) {
#pragma unroll
        for (int r = 0; r < 4; ++r) {
            pm[slot * 64 + rowb + r] = m_i[r];
            pl[slot * 64 + rowb + r] = l_i[r];
        }
    }
}

// ---------------------------------------------------------------------------
// Merge partials (unchanged this round)
// ---------------------------------------------------------------------------
__global__ __launch_bounds__(256) void attn_merge_kernel(
    const float* __restrict__ pO, const float* __restrict__ pm, const float* __restrict__ pl,
    float* __restrict__ out)
{
    const int qt = blockIdx.x;
    const int b  = blockIdx.y;
    const int nc = (qt + 8) >> 3;
    const int g = qt >> 3, rr = qt & 7;
    const int s0 = b * SLOTS_PER_B + 4 * g * (g + 1) + rr * (g + 1);

    const int t   = threadIdx.x;
    const int row = t >> 2;
    const int c0  = (t & 3) << 4;

    float mstar = -1e30f;
    for (int c = 0; c < nc; ++c)
        mstar = fmaxf(mstar, pm[(s0 + c) * 64 + row]);

    f32x4 acc[4];
#pragma unroll
    for (int i = 0; i < 4; ++i) acc[i] = f32x4{0.f, 0.f, 0.f, 0.f};
    float lsum = 0.f;

    for (int c = 0; c < nc; ++c) {
        const float w = __expf(pm[(s0 + c) * 64 + row] - mstar);
        lsum += w * pl[(s0 + c) * 64 + row];
        const float* p = pO + (size_t)(s0 + c) * 4096 + row * 64 + c0;
#pragma unroll
        for (int i = 0; i < 4; ++i) {
            f32x4 v = *(const f32x4*)(p + i * 4);
            acc[i] += w * v;
        }
    }

    const float inv = 1.0f / lsum;
    float* og = out + (size_t)b * SEQ * DH + (size_t)(qt * 64 + row) * DH + c0;
#pragma unroll
    for (int i = 0; i < 4; ++i)
        *(f32x4*)(og + i * 4) = acc[i] * inv;
}

extern "C" void kernel_launch(void* const* d_in, const int* in_sizes, int n_in,
                              void* d_out, int out_size, void* d_ws, size_t ws_size,
                              hipStream_t stream)
{
    (void)in_sizes; (void)n_in; (void)out_size; (void)ws_size;
    const float* q  = (const float*)d_in[0];
    const float* k  = (const float*)d_in[1];
    const float* v  = (const float*)d_in[2];
    const float* Wq = (const float*)d_in[3];
    const float* bq = (const float*)d_in[4];
    const float* Wk = (const float*)d_in[5];
    const float* bk = (const float*)d_in[6];
    const float* Wv = (const float*)d_in[7];
    const float* bv = (const float*)d_in[8];
    float* out = (float*)d_out;

    unsigned short* qh  = (unsigned short*)d_ws;
    unsigned short* kh  = qh + (size_t)NB * SEQ * DH;
    unsigned short* vhT = kh + (size_t)NB * SEQ * DH;
    float* pO = (float*)(vhT + (size_t)NB * SEQ * DH);
    float* pm = pO + (size_t)NB * SLOTS_PER_B * 4096;
    float* pl = pm + (size_t)NB * SLOTS_PER_B * 64;
    // Wfb aliases the START of pO: written by wprep, read by proj, then the
    // region is overwritten by attn_split's partials (stream-ordered, safe).
    // Keeps total workspace footprint identical to the verified baseline.
    unsigned short* Wfb = (unsigned short*)pO;

    wprep_kernel<<<dim3(16, 3), 256, 0, stream>>>(Wq, Wk, Wv, Wfb);
    proj_kernel<<<dim3(NB * SEQ / 64, 3), 256, 0, stream>>>(
        q, k, v, Wfb, bq, bk, bv, qh, kh, vhT);
    attn_split_kernel<<<dim3(8, SEQ / 64, NB), 256, 0, stream>>>(qh, kh, vhT, pO, pm, pl);
    attn_merge_kernel<<<dim3(SEQ / 64, NB), 256, 0, stream>>>(pO, pm, pl, out);
}